// Round 9
// baseline (344.815 us; speedup 1.0000x reference)
//
#include <hip/hip_runtime.h>

#define BN_EPS 1e-5f

typedef __attribute__((ext_vector_type(8))) short bf16x8;
typedef __attribute__((ext_vector_type(4))) float f32x4;
typedef __attribute__((ext_vector_type(2))) float f32x2;

__device__ __forceinline__ short f2bf(float f) {
    union { float f; unsigned u; } v; v.f = f;
    unsigned r = (v.u + 0x7fffu + ((v.u >> 16) & 1u)) >> 16;
    return (short)r;
}
__device__ __forceinline__ float bflo(unsigned d) {
    union { unsigned u; float f; } v; v.u = d << 16; return v.f;
}
__device__ __forceinline__ float bfhi(unsigned d) {
    union { unsigned u; float f; } v; v.u = d & 0xffff0000u; return v.f;
}

// ---------------- fp8 e4m3 (OCP) encode/decode -----------------------------
#if __has_builtin(__builtin_amdgcn_cvt_pk_fp8_f32)
__device__ __forceinline__ unsigned char f32_to_fp8(float v) {
    int pk = __builtin_amdgcn_cvt_pk_fp8_f32(v, v, 0, false);
    return (unsigned char)(pk & 0xff);
}
#else
__device__ __forceinline__ unsigned char f32_to_fp8(float v) {
    unsigned u = __float_as_uint(v);
    unsigned s = (u >> 24) & 0x80;
    float af = fabsf(v);
    if (af > 448.f) return (unsigned char)(s | 0x7E);
    if (af < 0.0009765625f) return (unsigned char)s;      // < 2^-10 -> 0
    int e = ilogbf(af);
    if (e < -6) {                                         // subnormal
        int q = __float2int_rn(af * 512.f);
        return (unsigned char)(s | q);
    }
    float sc = ldexpf(af, 3 - e);                         // [8,16)
    int q = __float2int_rn(sc);
    if (q == 16) { q = 8; ++e; if (e > 8) return (unsigned char)(s | 0x7E); }
    return (unsigned char)(s | ((e + 7) << 3) | (q - 8));
}
#endif

#if __has_builtin(__builtin_amdgcn_cvt_pk_f32_fp8)
__device__ __forceinline__ void fp8x4_acc(unsigned d, float w,
                                          float& a0, float& a1, float& a2, float& a3) {
    f32x2 lo = __builtin_amdgcn_cvt_pk_f32_fp8(d, false);
    f32x2 hi = __builtin_amdgcn_cvt_pk_f32_fp8(d, true);
    a0 = fmaf(w, lo[0], a0); a1 = fmaf(w, lo[1], a1);
    a2 = fmaf(w, hi[0], a2); a3 = fmaf(w, hi[1], a3);
}
#else
__device__ __forceinline__ float fp8dec(unsigned byte) {
    // e4m3fn: bits = (em<<20), f32 mul by 2^120; subnormals may FTZ (tiny, ok)
    unsigned em = byte & 0x7f;
    float m = __uint_as_float(em << 20) * 1.3292279957849159e36f;  // 2^120
    unsigned r = __float_as_uint(m) | ((byte & 0x80u) << 24);
    return __uint_as_float(r);
}
__device__ __forceinline__ void fp8x4_acc(unsigned d, float w,
                                          float& a0, float& a1, float& a2, float& a3) {
    a0 = fmaf(w, fp8dec(d & 0xff), a0);
    a1 = fmaf(w, fp8dec((d >> 8) & 0xff), a1);
    a2 = fmaf(w, fp8dec((d >> 16) & 0xff), a2);
    a3 = fmaf(w, fp8dec(d >> 24), a3);
}
#endif

// ---------------------------------------------------------------------------
// Fused prologue (single dispatch): CSR offsets + W transposes + zero stats.
// ---------------------------------------------------------------------------
__global__ __launch_bounds__(256) void prologue_k(const int* __restrict__ dst,
                                                  int* __restrict__ off, int E, int N,
                                                  const float* __restrict__ W0, short* __restrict__ Wt0,
                                                  const float* __restrict__ W1, short* __restrict__ Wt1,
                                                  const float* __restrict__ W2, short* __restrict__ Wt2,
                                                  float* __restrict__ stats) {
    int b = blockIdx.x;
    const int nbOff = (E + 256) / 256;
    if (b < nbOff) {
        int i = b * 256 + threadIdx.x;
        if (i > E) return;
        int cur  = (i < E) ? dst[i] : N;
        int prev = (i == 0) ? -1 : dst[i - 1];
        for (int n = prev + 1; n <= cur; ++n) off[n] = i;
        return;
    }
    b -= nbOff;
    if (b < 64) {                       // W0: 128x128
        int i = b * 256 + threadIdx.x;
        int c = i / 128, k = i % 128;
        Wt0[i] = f2bf(W0[k * 128 + c]);
        return;
    }
    b -= 64;
    if (b < 64) {                       // W1: 128x128
        int i = b * 256 + threadIdx.x;
        int c = i / 128, k = i % 128;
        Wt1[i] = f2bf(W1[k * 128 + c]);
        return;
    }
    b -= 64;
    if (b < 32) {                       // W2: 128x64 -> Wt2[64][128]
        int i = b * 256 + threadIdx.x;
        int c = i / 128, k = i % 128;
        Wt2[i] = f2bf(W2[k * 64 + c]);
        return;
    }
    b -= 32;
    if (b == 0) {                       // zero stats0+stats1
        stats[threadIdx.x] = 0.f;
        stats[threadIdx.x + 256] = 0.f;
    }
}

// ---------------------------------------------------------------------------
// MFMA GEMM, A-input fusion modes (BN finalize folded into MODE 1/2):
//   MODE 0: A = bf16(X fp32)                                   (layer 0)
//   MODE 1: A = relu(Hb*sc+sh + R_fp32); also write A -> X1    (layer 1)
//   MODE 2: A = relu(Hb*sc+sh + R_bf16)                        (layer 2)
// OUT8: write M as fp8 e4m3 (layers 0/1) else bf16 (layer 2).
// Block = 256 thr (4 waves), 128 rows. mfma_f32_16x16x32_bf16 (m89-verified).
// ---------------------------------------------------------------------------
template <int OUTC, int MODE, bool OUT8>
__global__ __launch_bounds__(256) void mgemm_k(const void* __restrict__ Xp,
                                               const short* __restrict__ Wt,
                                               void* __restrict__ Mout,
                                               const float* __restrict__ stats,
                                               const float* __restrict__ gamma,
                                               const float* __restrict__ beta,
                                               float invN,
                                               const void* __restrict__ Rp,
                                               short* __restrict__ X1, int N) {
    constexpr int NR = OUTC / 16;
    __shared__ short sW[OUTC][136];          // 272B stride: 2-way conflict = free
    __shared__ float sSS[256];

    const int tid = threadIdx.x;
    if constexpr (MODE != 0) {
        if (tid < 128) {
            float mu  = stats[tid] * invN;
            float var = fmaf(-mu, mu, stats[128 + tid] * invN);
            float sc  = gamma[tid] * rsqrtf(var + BN_EPS);
            sSS[tid]       = sc;
            sSS[128 + tid] = fmaf(-mu, sc, beta[tid]);
        }
    }
    for (int q = tid; q < OUTC * 16; q += 256) {
        int r = q >> 4, s = q & 15;
        *(int4*)&sW[r][s * 8] = ((const int4*)Wt)[q];
    }
    __syncthreads();

    const int wave = tid >> 6, lane = tid & 63;
    const int lr = lane & 15, lg = lane >> 4;
    const int row0 = blockIdx.x * 128 + wave * 32;

    f32x4 acc[2][NR];
    #pragma unroll
    for (int m = 0; m < 2; ++m)
        #pragma unroll
        for (int n = 0; n < NR; ++n) acc[m][n] = (f32x4){0.f, 0.f, 0.f, 0.f};

    #pragma unroll
    for (int kk = 0; kk < 4; ++kk) {
        bf16x8 a[2];
        const int ch0 = kk * 32 + lg * 8;
        #pragma unroll
        for (int m = 0; m < 2; ++m) {
            int row = row0 + m * 16 + lr;
            float v[8] = {0.f, 0.f, 0.f, 0.f, 0.f, 0.f, 0.f, 0.f};
            if (row < N) {
                if constexpr (MODE == 0) {
                    const float4* p = (const float4*)((const float*)Xp + (size_t)row * 128 + ch0);
                    float4 h0 = p[0], h1 = p[1];
                    v[0] = h0.x; v[1] = h0.y; v[2] = h0.z; v[3] = h0.w;
                    v[4] = h1.x; v[5] = h1.y; v[6] = h1.z; v[7] = h1.w;
                } else {
                    int4 hb = *(const int4*)((const short*)Xp + (size_t)row * 128 + ch0);
                    v[0] = bflo(hb.x); v[1] = bfhi(hb.x);
                    v[2] = bflo(hb.y); v[3] = bfhi(hb.y);
                    v[4] = bflo(hb.z); v[5] = bfhi(hb.z);
                    v[6] = bflo(hb.w); v[7] = bfhi(hb.w);
                    float sc[8], sh[8];
                    #pragma unroll
                    for (int k = 0; k < 8; ++k) {
                        sc[k] = sSS[ch0 + k];
                        sh[k] = sSS[128 + ch0 + k];
                    }
                    float r[8];
                    if constexpr (MODE == 1) {
                        const float4* rp = (const float4*)((const float*)Rp + (size_t)row * 128 + ch0);
                        float4 r0 = rp[0], r1 = rp[1];
                        r[0] = r0.x; r[1] = r0.y; r[2] = r0.z; r[3] = r0.w;
                        r[4] = r1.x; r[5] = r1.y; r[6] = r1.z; r[7] = r1.w;
                    } else {
                        int4 rb = *(const int4*)((const short*)Rp + (size_t)row * 128 + ch0);
                        r[0] = bflo(rb.x); r[1] = bfhi(rb.x);
                        r[2] = bflo(rb.y); r[3] = bfhi(rb.y);
                        r[4] = bflo(rb.z); r[5] = bfhi(rb.z);
                        r[6] = bflo(rb.w); r[7] = bfhi(rb.w);
                    }
                    #pragma unroll
                    for (int k = 0; k < 8; ++k)
                        v[k] = fmaxf(fmaf(v[k], sc[k], sh[k]) + r[k], 0.f);
                }
            }
            #pragma unroll
            for (int k = 0; k < 8; ++k) a[m][k] = f2bf(v[k]);
            if constexpr (MODE == 1) {
                if (row < N) *(bf16x8*)&X1[(size_t)row * 128 + ch0] = a[m];
            }
        }
        #pragma unroll
        for (int n = 0; n < NR; ++n) {
            bf16x8 b = *(const bf16x8*)&sW[n * 16 + lr][kk * 32 + lg * 8];
            acc[0][n] = __builtin_amdgcn_mfma_f32_16x16x32_bf16(a[0], b, acc[0][n], 0, 0, 0);
            acc[1][n] = __builtin_amdgcn_mfma_f32_16x16x32_bf16(a[1], b, acc[1][n], 0, 0, 0);
        }
    }

    #pragma unroll
    for (int m = 0; m < 2; ++m)
        #pragma unroll
        for (int r = 0; r < 4; ++r) {
            int row = row0 + m * 16 + lg * 4 + r;
            if (row < N) {
                if constexpr (OUT8) {
                    #pragma unroll
                    for (int n = 0; n < NR; ++n)
                        ((unsigned char*)Mout)[(size_t)row * OUTC + n * 16 + lr] =
                            f32_to_fp8(acc[m][n][r]);
                } else {
                    #pragma unroll
                    for (int n = 0; n < NR; ++n)
                        ((short*)Mout)[(size_t)row * OUTC + n * 16 + lr] = f2bf(acc[m][n][r]);
                }
            }
        }
}

// ---------------------------------------------------------------------------
// 128-ch segment-sum gather over fp8 M (row = 128 B). One node per wave.
// Lane = (e2 = lane>>5, c = lane&31): dword = 4 channels, 2 edges per load.
// 16-edge unconditional batches (8 loads, 2KB in flight) + lean weighted
// tail. Butterfly over bit 5 merges the two edge halves. Output Hb bf16.
// ---------------------------------------------------------------------------
__global__ __launch_bounds__(256) void aggf8_k(const unsigned char* __restrict__ M,
                                               const int* __restrict__ src,
                                               const int* __restrict__ off,
                                               const float* __restrict__ bias,
                                               unsigned* __restrict__ Hb, int N) {
    const int lane = threadIdx.x & 63;
    const int node = blockIdx.x * 4 + (threadIdx.x >> 6);
    if (node >= N) return;
    const int e0 = off[node], e1 = off[node + 1];
    const unsigned* __restrict__ M32 = (const unsigned*)M;   // 32 dwords/row
    const int e2 = lane >> 5, c = lane & 31;

    float a0 = 0.f, a1 = 0.f, a2 = 0.f, a3 = 0.f;
    for (int base = e0; base < e1; base += 64) {
        const int cnt = min(64, e1 - base);
        int s = (base + lane < e1) ? src[base + lane] : 0;
        const int full = cnt & ~15;
        for (int j = 0; j < full; j += 16) {
            unsigned d[8];
            #pragma unroll
            for (int i = 0; i < 8; ++i) {
                int si = __shfl(s, j + i * 2 + e2);
                d[i] = M32[(size_t)si * 32 + c];
            }
            #pragma unroll
            for (int i = 0; i < 8; ++i) fp8x4_acc(d[i], 1.f, a0, a1, a2, a3);
        }
        for (int j = full; j < cnt; j += 2) {
            int idx = j + e2;
            int ii  = idx < cnt ? idx : cnt - 1;
            int si  = __shfl(s, ii);
            unsigned d = M32[(size_t)si * 32 + c];
            float w = idx < cnt ? 1.f : 0.f;
            fp8x4_acc(d, w, a0, a1, a2, a3);
        }
    }
    a0 += __shfl_xor(a0, 32); a1 += __shfl_xor(a1, 32);
    a2 += __shfl_xor(a2, 32); a3 += __shfl_xor(a3, 32);
    if (e2 == 0) {
        float4 bv = *(const float4*)&bias[c * 4];
        uint2 o;
        o.x = (unsigned)(unsigned short)f2bf(a0 + bv.x)
            | ((unsigned)(unsigned short)f2bf(a1 + bv.y) << 16);
        o.y = (unsigned)(unsigned short)f2bf(a2 + bv.z)
            | ((unsigned)(unsigned short)f2bf(a3 + bv.w) << 16);
        *(uint2*)&Hb[(size_t)node * 64 + c * 2] = o;
    }
}

// ---------------------------------------------------------------------------
// 64-ch segment-sum gather over bf16 M2, fp32 out (final layer).
// 2 edges per load (e2 = lane>>5, dword = 2 ch), 8-deep batches.
// ---------------------------------------------------------------------------
__global__ __launch_bounds__(256) void agg64_k(const short* __restrict__ M,
                                               const int* __restrict__ src,
                                               const int* __restrict__ off,
                                               const float* __restrict__ bias,
                                               float* __restrict__ out, int N) {
    const int lane = threadIdx.x & 63;
    const int node = blockIdx.x * 4 + (threadIdx.x >> 6);
    if (node >= N) return;
    const int e0 = off[node], e1 = off[node + 1];
    const unsigned* __restrict__ M32 = (const unsigned*)M;   // 32 dwords/row
    const int e2 = lane >> 5, c = lane & 31;

    float accx = 0.f, accy = 0.f;
    for (int base = e0; base < e1; base += 64) {
        const int cnt = min(64, e1 - base);
        int s = (base + lane < e1) ? src[base + lane] : 0;
        const int full = cnt & ~15;
        for (int j = 0; j < full; j += 16) {
            unsigned d[8];
            #pragma unroll
            for (int i = 0; i < 8; ++i) {
                int si = __shfl(s, j + i * 2 + e2);
                d[i] = M32[(size_t)si * 32 + c];
            }
            #pragma unroll
            for (int i = 0; i < 8; ++i) { accx += bflo(d[i]); accy += bfhi(d[i]); }
        }
        for (int j = full; j < cnt; j += 2) {
            int idx = j + e2;
            int ii  = idx < cnt ? idx : cnt - 1;
            int si  = __shfl(s, ii);
            unsigned d = M32[(size_t)si * 32 + c];
            float w = idx < cnt ? 1.f : 0.f;
            accx = fmaf(w, bflo(d), accx);
            accy = fmaf(w, bfhi(d), accy);
        }
    }
    accx += __shfl_xor(accx, 32);
    accy += __shfl_xor(accy, 32);
    if (e2 == 0) {
        float2 bv = *(const float2*)&bias[c * 2];
        *(float2*)&out[(size_t)node * 64 + c * 2] = make_float2(accx + bv.x, accy + bv.y);
    }
}

// ---------------------------------------------------------------------------
// BN column stats (sum, sumsq) over bf16 Hb. Lane = dword (2 ch); wave reads
// contiguous 256B rows. Per-block LDS reduce -> 256 atomics.
// ---------------------------------------------------------------------------
__global__ __launch_bounds__(256) void stats_k(const short* __restrict__ Hb,
                                               float* __restrict__ stats, int N) {
    const int lane = threadIdx.x & 63, wave = threadIdx.x >> 6;
    const unsigned* __restrict__ H32 = (const unsigned*)Hb;
    float2 sum = make_float2(0.f, 0.f), sq = make_float2(0.f, 0.f);
    for (int r = blockIdx.x * 4 + wave; r < N; r += gridDim.x * 4) {
        unsigned d = H32[(size_t)r * 64 + lane];
        float lo = bflo(d), hi = bfhi(d);
        sum.x += lo; sum.y += hi;
        sq.x = fmaf(lo, lo, sq.x); sq.y = fmaf(hi, hi, sq.y);
    }
    __shared__ float sL[4][256];
    sL[wave][lane * 2]           = sum.x;
    sL[wave][lane * 2 + 1]       = sum.y;
    sL[wave][128 + lane * 2]     = sq.x;
    sL[wave][128 + lane * 2 + 1] = sq.y;
    __syncthreads();
    int tid = threadIdx.x;   // [0,128) -> sums, [128,256) -> sumsqs
    float v = sL[0][tid] + sL[1][tid] + sL[2][tid] + sL[3][tid];
    atomicAdd(&stats[tid], v);
}

// ---------------------------------------------------------------------------
extern "C" void kernel_launch(void* const* d_in, const int* in_sizes, int n_in,
                              void* d_out, int out_size, void* d_ws, size_t ws_size,
                              hipStream_t stream) {
    const float* x   = (const float*)d_in[0];
    const int*   src = (const int*)d_in[1];
    const int*   dst = (const int*)d_in[2];
    const float* W0  = (const float*)d_in[3];
    const float* b0  = (const float*)d_in[4];
    const float* W1  = (const float*)d_in[5];
    const float* b1  = (const float*)d_in[6];
    const float* W2  = (const float*)d_in[7];
    const float* b2  = (const float*)d_in[8];
    const float* g0  = (const float*)d_in[9];
    const float* be0 = (const float*)d_in[10];
    const float* g1  = (const float*)d_in[11];
    const float* be1 = (const float*)d_in[12];
    float* out = (float*)d_out;

    const int N = in_sizes[0] / 128;
    const int E = in_sizes[1];

    // workspace: M (N x 128 B: fp8 layers 0/1, bf16 64ch layer 2) +
    //            bf16 Hb (N x 128) + bf16 X1 (N x 128) + misc
    char*  ws   = (char*)d_ws;
    size_t bufH = (size_t)N * 128 * sizeof(short);
    char*  Mb = ws;                           // N x 128 bytes
    short* Hb = (short*)(ws + bufH);          // pre-BN agg output, bf16
    short* X1 = (short*)(ws + 2 * bufH);      // post-layer-1 activations, bf16
    size_t p  = 3 * bufH;
    p = (p + 255) & ~(size_t)255;
    int*   off = (int*)(ws + p);
    p += ((size_t)(N + 1) * sizeof(int) + 255) & ~(size_t)255;
    float* stats0 = (float*)(ws + p); p += 1024;   // contiguous with stats1
    float* stats1 = (float*)(ws + p); p += 1024;
    short* Wt0    = (short*)(ws + p); p += 128 * 128 * 2;
    short* Wt1    = (short*)(ws + p); p += 128 * 128 * 2;
    short* Wt2    = (short*)(ws + p); p += 128 * 64 * 2;

    const dim3 blk(256);
    const int nbOff  = (E + 256) / 256;
    const int gPro   = nbOff + 64 + 64 + 32 + 1;
    const int gGemm  = (N + 127) / 128;
    const int gAgg   = (N + 3) / 4;            // one node per wave
    const int gStats = 2048;
    const float invN = 1.f / (float)N;

    prologue_k<<<gPro, blk, 0, stream>>>(dst, off, E, N, W0, Wt0, W1, Wt1, W2, Wt2, stats0);

    // ---- layer 0 ----
    mgemm_k<128, 0, true><<<gGemm, blk, 0, stream>>>(x, Wt0, Mb, nullptr, nullptr, nullptr,
                                                     0.f, nullptr, nullptr, N);
    aggf8_k<<<gAgg, blk, 0, stream>>>((unsigned char*)Mb, src, off, b0, (unsigned*)Hb, N);
    stats_k<<<gStats, blk, 0, stream>>>(Hb, stats0, N);

    // ---- layer 1 (BN finalize folded into GEMM prologue) ----
    mgemm_k<128, 1, true><<<gGemm, blk, 0, stream>>>(Hb, Wt1, Mb, stats0, g0, be0, invN,
                                                     x, X1, N);
    aggf8_k<<<gAgg, blk, 0, stream>>>((unsigned char*)Mb, src, off, b1, (unsigned*)Hb, N);
    stats_k<<<gStats, blk, 0, stream>>>(Hb, stats1, N);

    // ---- layer 2 ----
    mgemm_k<64, 2, false><<<gGemm, blk, 0, stream>>>(Hb, Wt2, Mb, stats1, g1, be1, invN,
                                                     X1, nullptr, N);
    agg64_k<<<gAgg, blk, 0, stream>>>((short*)Mb, src, off, b2, out, N);
}

// Round 10
// 318.498 us; speedup vs baseline: 1.0826x; 1.0826x over previous
//
#include <hip/hip_runtime.h>

#define BN_EPS 1e-5f

typedef __attribute__((ext_vector_type(8))) short bf16x8;
typedef __attribute__((ext_vector_type(4))) float f32x4;
typedef __attribute__((ext_vector_type(2))) float f32x2;

__device__ __forceinline__ short f2bf(float f) {
    union { float f; unsigned u; } v; v.f = f;
    unsigned r = (v.u + 0x7fffu + ((v.u >> 16) & 1u)) >> 16;
    return (short)r;
}
__device__ __forceinline__ float bflo(unsigned d) {
    union { unsigned u; float f; } v; v.u = d << 16; return v.f;
}
__device__ __forceinline__ float bfhi(unsigned d) {
    union { unsigned u; float f; } v; v.u = d & 0xffff0000u; return v.f;
}

// ---------------- fp8 e4m3 (OCP) encode/decode -----------------------------
#if __has_builtin(__builtin_amdgcn_cvt_pk_fp8_f32)
__device__ __forceinline__ unsigned char f32_to_fp8(float v) {
    int pk = __builtin_amdgcn_cvt_pk_fp8_f32(v, v, 0, false);
    return (unsigned char)(pk & 0xff);
}
#else
__device__ __forceinline__ unsigned char f32_to_fp8(float v) {
    unsigned u = __float_as_uint(v);
    unsigned s = (u >> 24) & 0x80;
    float af = fabsf(v);
    if (af > 448.f) return (unsigned char)(s | 0x7E);
    if (af < 0.0009765625f) return (unsigned char)s;
    int e = ilogbf(af);
    if (e < -6) {
        int q = __float2int_rn(af * 512.f);
        return (unsigned char)(s | q);
    }
    float sc = ldexpf(af, 3 - e);
    int q = __float2int_rn(sc);
    if (q == 16) { q = 8; ++e; if (e > 8) return (unsigned char)(s | 0x7E); }
    return (unsigned char)(s | ((e + 7) << 3) | (q - 8));
}
#endif

#if __has_builtin(__builtin_amdgcn_cvt_pk_f32_fp8)
__device__ __forceinline__ void fp8x4_acc(unsigned d, float w,
                                          float& a0, float& a1, float& a2, float& a3) {
    f32x2 lo = __builtin_amdgcn_cvt_pk_f32_fp8(d, false);
    f32x2 hi = __builtin_amdgcn_cvt_pk_f32_fp8(d, true);
    a0 = fmaf(w, lo[0], a0); a1 = fmaf(w, lo[1], a1);
    a2 = fmaf(w, hi[0], a2); a3 = fmaf(w, hi[1], a3);
}
#else
__device__ __forceinline__ float fp8dec(unsigned byte) {
    unsigned em = byte & 0x7f;
    float m = __uint_as_float(em << 20) * 1.3292279957849159e36f;  // 2^120
    unsigned r = __float_as_uint(m) | ((byte & 0x80u) << 24);
    return __uint_as_float(r);
}
__device__ __forceinline__ void fp8x4_acc(unsigned d, float w,
                                          float& a0, float& a1, float& a2, float& a3) {
    a0 = fmaf(w, fp8dec(d & 0xff), a0);
    a1 = fmaf(w, fp8dec((d >> 8) & 0xff), a1);
    a2 = fmaf(w, fp8dec((d >> 16) & 0xff), a2);
    a3 = fmaf(w, fp8dec(d >> 24), a3);
}
#endif

// ---------------------------------------------------------------------------
// Fused prologue (single dispatch): CSR offsets + W transposes + zero stats.
// ---------------------------------------------------------------------------
__global__ __launch_bounds__(256) void prologue_k(const int* __restrict__ dst,
                                                  int* __restrict__ off, int E, int N,
                                                  const float* __restrict__ W0, short* __restrict__ Wt0,
                                                  const float* __restrict__ W1, short* __restrict__ Wt1,
                                                  const float* __restrict__ W2, short* __restrict__ Wt2,
                                                  float* __restrict__ stats) {
    int b = blockIdx.x;
    const int nbOff = (E + 256) / 256;
    if (b < nbOff) {
        int i = b * 256 + threadIdx.x;
        if (i > E) return;
        int cur  = (i < E) ? dst[i] : N;
        int prev = (i == 0) ? -1 : dst[i - 1];
        for (int n = prev + 1; n <= cur; ++n) off[n] = i;
        return;
    }
    b -= nbOff;
    if (b < 64) {
        int i = b * 256 + threadIdx.x;
        int c = i / 128, k = i % 128;
        Wt0[i] = f2bf(W0[k * 128 + c]);
        return;
    }
    b -= 64;
    if (b < 64) {
        int i = b * 256 + threadIdx.x;
        int c = i / 128, k = i % 128;
        Wt1[i] = f2bf(W1[k * 128 + c]);
        return;
    }
    b -= 64;
    if (b < 32) {
        int i = b * 256 + threadIdx.x;
        int c = i / 128, k = i % 128;
        Wt2[i] = f2bf(W2[k * 64 + c]);
        return;
    }
    b -= 32;
    if (b == 0) {
        stats[threadIdx.x] = 0.f;
        stats[threadIdx.x + 256] = 0.f;
    }
}

// ---------------------------------------------------------------------------
// MFMA GEMM, A-input fusion modes (BN finalize folded into MODE 1/2).
// ---------------------------------------------------------------------------
template <int OUTC, int MODE, bool OUT8>
__global__ __launch_bounds__(256) void mgemm_k(const void* __restrict__ Xp,
                                               const short* __restrict__ Wt,
                                               void* __restrict__ Mout,
                                               const float* __restrict__ stats,
                                               const float* __restrict__ gamma,
                                               const float* __restrict__ beta,
                                               float invN,
                                               const void* __restrict__ Rp,
                                               short* __restrict__ X1, int N) {
    constexpr int NR = OUTC / 16;
    __shared__ short sW[OUTC][136];
    __shared__ float sSS[256];

    const int tid = threadIdx.x;
    if constexpr (MODE != 0) {
        if (tid < 128) {
            float mu  = stats[tid] * invN;
            float var = fmaf(-mu, mu, stats[128 + tid] * invN);
            float sc  = gamma[tid] * rsqrtf(var + BN_EPS);
            sSS[tid]       = sc;
            sSS[128 + tid] = fmaf(-mu, sc, beta[tid]);
        }
    }
    for (int q = tid; q < OUTC * 16; q += 256) {
        int r = q >> 4, s = q & 15;
        *(int4*)&sW[r][s * 8] = ((const int4*)Wt)[q];
    }
    __syncthreads();

    const int wave = tid >> 6, lane = tid & 63;
    const int lr = lane & 15, lg = lane >> 4;
    const int row0 = blockIdx.x * 128 + wave * 32;

    f32x4 acc[2][NR];
    #pragma unroll
    for (int m = 0; m < 2; ++m)
        #pragma unroll
        for (int n = 0; n < NR; ++n) acc[m][n] = (f32x4){0.f, 0.f, 0.f, 0.f};

    #pragma unroll
    for (int kk = 0; kk < 4; ++kk) {
        bf16x8 a[2];
        const int ch0 = kk * 32 + lg * 8;
        #pragma unroll
        for (int m = 0; m < 2; ++m) {
            int row = row0 + m * 16 + lr;
            float v[8] = {0.f, 0.f, 0.f, 0.f, 0.f, 0.f, 0.f, 0.f};
            if (row < N) {
                if constexpr (MODE == 0) {
                    const float4* p = (const float4*)((const float*)Xp + (size_t)row * 128 + ch0);
                    float4 h0 = p[0], h1 = p[1];
                    v[0] = h0.x; v[1] = h0.y; v[2] = h0.z; v[3] = h0.w;
                    v[4] = h1.x; v[5] = h1.y; v[6] = h1.z; v[7] = h1.w;
                } else {
                    int4 hb = *(const int4*)((const short*)Xp + (size_t)row * 128 + ch0);
                    v[0] = bflo(hb.x); v[1] = bfhi(hb.x);
                    v[2] = bflo(hb.y); v[3] = bfhi(hb.y);
                    v[4] = bflo(hb.z); v[5] = bfhi(hb.z);
                    v[6] = bflo(hb.w); v[7] = bfhi(hb.w);
                    float sc[8], sh[8];
                    #pragma unroll
                    for (int k = 0; k < 8; ++k) {
                        sc[k] = sSS[ch0 + k];
                        sh[k] = sSS[128 + ch0 + k];
                    }
                    float r[8];
                    if constexpr (MODE == 1) {
                        const float4* rp = (const float4*)((const float*)Rp + (size_t)row * 128 + ch0);
                        float4 r0 = rp[0], r1 = rp[1];
                        r[0] = r0.x; r[1] = r0.y; r[2] = r0.z; r[3] = r0.w;
                        r[4] = r1.x; r[5] = r1.y; r[6] = r1.z; r[7] = r1.w;
                    } else {
                        int4 rb = *(const int4*)((const short*)Rp + (size_t)row * 128 + ch0);
                        r[0] = bflo(rb.x); r[1] = bfhi(rb.x);
                        r[2] = bflo(rb.y); r[3] = bfhi(rb.y);
                        r[4] = bflo(rb.z); r[5] = bfhi(rb.z);
                        r[6] = bflo(rb.w); r[7] = bfhi(rb.w);
                    }
                    #pragma unroll
                    for (int k = 0; k < 8; ++k)
                        v[k] = fmaxf(fmaf(v[k], sc[k], sh[k]) + r[k], 0.f);
                }
            }
            #pragma unroll
            for (int k = 0; k < 8; ++k) a[m][k] = f2bf(v[k]);
            if constexpr (MODE == 1) {
                if (row < N) *(bf16x8*)&X1[(size_t)row * 128 + ch0] = a[m];
            }
        }
        #pragma unroll
        for (int n = 0; n < NR; ++n) {
            bf16x8 b = *(const bf16x8*)&sW[n * 16 + lr][kk * 32 + lg * 8];
            acc[0][n] = __builtin_amdgcn_mfma_f32_16x16x32_bf16(a[0], b, acc[0][n], 0, 0, 0);
            acc[1][n] = __builtin_amdgcn_mfma_f32_16x16x32_bf16(a[1], b, acc[1][n], 0, 0, 0);
        }
    }

    #pragma unroll
    for (int m = 0; m < 2; ++m)
        #pragma unroll
        for (int r = 0; r < 4; ++r) {
            int row = row0 + m * 16 + lg * 4 + r;
            if (row < N) {
                if constexpr (OUT8) {
                    #pragma unroll
                    for (int n = 0; n < NR; ++n)
                        ((unsigned char*)Mout)[(size_t)row * OUTC + n * 16 + lr] =
                            f32_to_fp8(acc[m][n][r]);
                } else {
                    #pragma unroll
                    for (int n = 0; n < NR; ++n)
                        ((short*)Mout)[(size_t)row * OUTC + n * 16 + lr] = f2bf(acc[m][n][r]);
                }
            }
        }
}

// ---- slow-path helpers (degree > 64; statistically never taken) -----------
__device__ __noinline__ void aggf8_one(const unsigned* __restrict__ M32,
                                       const int* __restrict__ src,
                                       int e0, int e1, int lane, int e2, int c,
                                       float& a0, float& a1, float& a2, float& a3) {
    for (int base = e0; base < e1; base += 64) {
        int cnt = min(64, e1 - base);
        int s = (base + lane < e1) ? src[base + lane] : 0;
        for (int j = 0; j < cnt; j += 2) {
            int idx = j + e2;
            int ii  = idx < cnt ? idx : cnt - 1;
            int si  = __shfl(s, ii);
            unsigned d = M32[(size_t)si * 32 + c];
            float w = idx < cnt ? 1.f : 0.f;
            fp8x4_acc(d, w, a0, a1, a2, a3);
        }
    }
}
__device__ __noinline__ void aggbf_one(const unsigned* __restrict__ M32,
                                       const int* __restrict__ src,
                                       int e0, int e1, int lane, int e2, int c,
                                       float& ax, float& ay) {
    for (int base = e0; base < e1; base += 64) {
        int cnt = min(64, e1 - base);
        int s = (base + lane < e1) ? src[base + lane] : 0;
        for (int j = 0; j < cnt; j += 2) {
            int idx = j + e2;
            int ii  = idx < cnt ? idx : cnt - 1;
            int si  = __shfl(s, ii);
            unsigned d = M32[(size_t)si * 32 + c];
            float w = idx < cnt ? 1.f : 0.f;
            ax = fmaf(w, bflo(d), ax);
            ay = fmaf(w, bfhi(d), ay);
        }
    }
}

// ---------------------------------------------------------------------------
// 128-ch fp8 gather, TWO NODES PER WAVE (A, B = consecutive). Per 16-edge
// batch: 8 clamped/weighted loads per node (16 outstanding, 2 indep chains).
// Butterfly bit5; lanes e2=0 store A, e2=1 store B. Output Hb bf16.
// ---------------------------------------------------------------------------
__global__ __launch_bounds__(256) void aggf8_k(const unsigned char* __restrict__ M,
                                               const int* __restrict__ src,
                                               const int* __restrict__ off,
                                               const float* __restrict__ bias,
                                               unsigned* __restrict__ Hb, int N) {
    const int lane = threadIdx.x & 63;
    const int e2 = lane >> 5, c = lane & 31;
    const int nA = (blockIdx.x * 4 + (threadIdx.x >> 6)) * 2;
    if (nA >= N) return;
    const bool hasB = nA + 1 < N;
    const int e0A = off[nA], e1A = off[nA + 1];
    const int e0B = e1A, e1B = hasB ? off[nA + 2] : e1A;
    const unsigned* __restrict__ M32 = (const unsigned*)M;

    float aA0 = 0.f, aA1 = 0.f, aA2 = 0.f, aA3 = 0.f;
    float aB0 = 0.f, aB1 = 0.f, aB2 = 0.f, aB3 = 0.f;
    const int dgA = e1A - e0A, dgB = e1B - e0B;

    if (dgA <= 64 && dgB <= 64) {
        int sA = (e0A + lane < e1A) ? src[e0A + lane] : 0;
        int sB = (e0B + lane < e1B) ? src[e0B + lane] : 0;
        const int jmax = max(dgA, dgB);
        for (int j = 0; j < jmax; j += 16) {
            unsigned dA[8], dB[8];
            float wA[8], wB[8];
            #pragma unroll
            for (int i = 0; i < 8; ++i) {
                int idx = j + i * 2 + e2;
                int iA = max(min(idx, dgA - 1), 0);
                int iB = max(min(idx, dgB - 1), 0);
                int siA = __shfl(sA, iA);
                int siB = __shfl(sB, iB);
                dA[i] = M32[(size_t)siA * 32 + c];
                dB[i] = M32[(size_t)siB * 32 + c];
                wA[i] = idx < dgA ? 1.f : 0.f;
                wB[i] = idx < dgB ? 1.f : 0.f;
            }
            #pragma unroll
            for (int i = 0; i < 8; ++i) {
                fp8x4_acc(dA[i], wA[i], aA0, aA1, aA2, aA3);
                fp8x4_acc(dB[i], wB[i], aB0, aB1, aB2, aB3);
            }
        }
    } else {
        aggf8_one(M32, src, e0A, e1A, lane, e2, c, aA0, aA1, aA2, aA3);
        aggf8_one(M32, src, e0B, e1B, lane, e2, c, aB0, aB1, aB2, aB3);
    }

    aA0 += __shfl_xor(aA0, 32); aA1 += __shfl_xor(aA1, 32);
    aA2 += __shfl_xor(aA2, 32); aA3 += __shfl_xor(aA3, 32);
    aB0 += __shfl_xor(aB0, 32); aB1 += __shfl_xor(aB1, 32);
    aB2 += __shfl_xor(aB2, 32); aB3 += __shfl_xor(aB3, 32);

    float4 bv = *(const float4*)&bias[c * 4];
    if (e2 == 0) {
        uint2 o;
        o.x = (unsigned)(unsigned short)f2bf(aA0 + bv.x)
            | ((unsigned)(unsigned short)f2bf(aA1 + bv.y) << 16);
        o.y = (unsigned)(unsigned short)f2bf(aA2 + bv.z)
            | ((unsigned)(unsigned short)f2bf(aA3 + bv.w) << 16);
        *(uint2*)&Hb[(size_t)nA * 64 + c * 2] = o;
    } else if (hasB) {
        uint2 o;
        o.x = (unsigned)(unsigned short)f2bf(aB0 + bv.x)
            | ((unsigned)(unsigned short)f2bf(aB1 + bv.y) << 16);
        o.y = (unsigned)(unsigned short)f2bf(aB2 + bv.z)
            | ((unsigned)(unsigned short)f2bf(aB3 + bv.w) << 16);
        *(uint2*)&Hb[(size_t)(nA + 1) * 64 + c * 2] = o;
    }
}

// ---------------------------------------------------------------------------
// 64-ch bf16 gather, fp32 out, TWO NODES PER WAVE (same structure).
// ---------------------------------------------------------------------------
__global__ __launch_bounds__(256) void agg64_k(const short* __restrict__ M,
                                               const int* __restrict__ src,
                                               const int* __restrict__ off,
                                               const float* __restrict__ bias,
                                               float* __restrict__ out, int N) {
    const int lane = threadIdx.x & 63;
    const int e2 = lane >> 5, c = lane & 31;
    const int nA = (blockIdx.x * 4 + (threadIdx.x >> 6)) * 2;
    if (nA >= N) return;
    const bool hasB = nA + 1 < N;
    const int e0A = off[nA], e1A = off[nA + 1];
    const int e0B = e1A, e1B = hasB ? off[nA + 2] : e1A;
    const unsigned* __restrict__ M32 = (const unsigned*)M;

    float aAx = 0.f, aAy = 0.f, aBx = 0.f, aBy = 0.f;
    const int dgA = e1A - e0A, dgB = e1B - e0B;

    if (dgA <= 64 && dgB <= 64) {
        int sA = (e0A + lane < e1A) ? src[e0A + lane] : 0;
        int sB = (e0B + lane < e1B) ? src[e0B + lane] : 0;
        const int jmax = max(dgA, dgB);
        for (int j = 0; j < jmax; j += 16) {
            unsigned dA[8], dB[8];
            float wA[8], wB[8];
            #pragma unroll
            for (int i = 0; i < 8; ++i) {
                int idx = j + i * 2 + e2;
                int iA = max(min(idx, dgA - 1), 0);
                int iB = max(min(idx, dgB - 1), 0);
                int siA = __shfl(sA, iA);
                int siB = __shfl(sB, iB);
                dA[i] = M32[(size_t)siA * 32 + c];
                dB[i] = M32[(size_t)siB * 32 + c];
                wA[i] = idx < dgA ? 1.f : 0.f;
                wB[i] = idx < dgB ? 1.f : 0.f;
            }
            #pragma unroll
            for (int i = 0; i < 8; ++i) {
                aAx = fmaf(wA[i], bflo(dA[i]), aAx);
                aAy = fmaf(wA[i], bfhi(dA[i]), aAy);
                aBx = fmaf(wB[i], bflo(dB[i]), aBx);
                aBy = fmaf(wB[i], bfhi(dB[i]), aBy);
            }
        }
    } else {
        aggbf_one(M32, src, e0A, e1A, lane, e2, c, aAx, aAy);
        aggbf_one(M32, src, e0B, e1B, lane, e2, c, aBx, aBy);
    }

    aAx += __shfl_xor(aAx, 32); aAy += __shfl_xor(aAy, 32);
    aBx += __shfl_xor(aBx, 32); aBy += __shfl_xor(aBy, 32);

    float2 bv = *(const float2*)&bias[c * 2];
    if (e2 == 0) {
        *(float2*)&out[(size_t)nA * 64 + c * 2] = make_float2(aAx + bv.x, aAy + bv.y);
    } else if (hasB) {
        *(float2*)&out[(size_t)(nA + 1) * 64 + c * 2] = make_float2(aBx + bv.x, aBy + bv.y);
    }
}

// ---------------------------------------------------------------------------
// BN column stats (sum, sumsq) over bf16 Hb.
// ---------------------------------------------------------------------------
__global__ __launch_bounds__(256) void stats_k(const short* __restrict__ Hb,
                                               float* __restrict__ stats, int N) {
    const int lane = threadIdx.x & 63, wave = threadIdx.x >> 6;
    const unsigned* __restrict__ H32 = (const unsigned*)Hb;
    float2 sum = make_float2(0.f, 0.f), sq = make_float2(0.f, 0.f);
    for (int r = blockIdx.x * 4 + wave; r < N; r += gridDim.x * 4) {
        unsigned d = H32[(size_t)r * 64 + lane];
        float lo = bflo(d), hi = bfhi(d);
        sum.x += lo; sum.y += hi;
        sq.x = fmaf(lo, lo, sq.x); sq.y = fmaf(hi, hi, sq.y);
    }
    __shared__ float sL[4][256];
    sL[wave][lane * 2]           = sum.x;
    sL[wave][lane * 2 + 1]       = sum.y;
    sL[wave][128 + lane * 2]     = sq.x;
    sL[wave][128 + lane * 2 + 1] = sq.y;
    __syncthreads();
    int tid = threadIdx.x;
    float v = sL[0][tid] + sL[1][tid] + sL[2][tid] + sL[3][tid];
    atomicAdd(&stats[tid], v);
}

// ---------------------------------------------------------------------------
extern "C" void kernel_launch(void* const* d_in, const int* in_sizes, int n_in,
                              void* d_out, int out_size, void* d_ws, size_t ws_size,
                              hipStream_t stream) {
    const float* x   = (const float*)d_in[0];
    const int*   src = (const int*)d_in[1];
    const int*   dst = (const int*)d_in[2];
    const float* W0  = (const float*)d_in[3];
    const float* b0  = (const float*)d_in[4];
    const float* W1  = (const float*)d_in[5];
    const float* b1  = (const float*)d_in[6];
    const float* W2  = (const float*)d_in[7];
    const float* b2  = (const float*)d_in[8];
    const float* g0  = (const float*)d_in[9];
    const float* be0 = (const float*)d_in[10];
    const float* g1  = (const float*)d_in[11];
    const float* be1 = (const float*)d_in[12];
    float* out = (float*)d_out;

    const int N = in_sizes[0] / 128;
    const int E = in_sizes[1];

    char*  ws   = (char*)d_ws;
    size_t bufH = (size_t)N * 128 * sizeof(short);
    char*  Mb = ws;                           // N x 128 bytes (fp8 or bf16-64ch)
    short* Hb = (short*)(ws + bufH);          // pre-BN agg output, bf16
    short* X1 = (short*)(ws + 2 * bufH);      // post-layer-1 activations, bf16
    size_t p  = 3 * bufH;
    p = (p + 255) & ~(size_t)255;
    int*   off = (int*)(ws + p);
    p += ((size_t)(N + 1) * sizeof(int) + 255) & ~(size_t)255;
    float* stats0 = (float*)(ws + p); p += 1024;
    float* stats1 = (float*)(ws + p); p += 1024;
    short* Wt0    = (short*)(ws + p); p += 128 * 128 * 2;
    short* Wt1    = (short*)(ws + p); p += 128 * 128 * 2;
    short* Wt2    = (short*)(ws + p); p += 128 * 64 * 2;

    const dim3 blk(256);
    const int nbOff  = (E + 256) / 256;
    const int gPro   = nbOff + 64 + 64 + 32 + 1;
    const int gGemm  = (N + 127) / 128;
    const int gAgg   = (N + 7) / 8;            // two nodes per wave
    const int gStats = 2048;
    const float invN = 1.f / (float)N;

    prologue_k<<<gPro, blk, 0, stream>>>(dst, off, E, N, W0, Wt0, W1, Wt1, W2, Wt2, stats0);

    // ---- layer 0 ----
    mgemm_k<128, 0, true><<<gGemm, blk, 0, stream>>>(x, Wt0, Mb, nullptr, nullptr, nullptr,
                                                     0.f, nullptr, nullptr, N);
    aggf8_k<<<gAgg, blk, 0, stream>>>((unsigned char*)Mb, src, off, b0, (unsigned*)Hb, N);
    stats_k<<<gStats, blk, 0, stream>>>(Hb, stats0, N);

    // ---- layer 1 ----
    mgemm_k<128, 1, true><<<gGemm, blk, 0, stream>>>(Hb, Wt1, Mb, stats0, g0, be0, invN,
                                                     x, X1, N);
    aggf8_k<<<gAgg, blk, 0, stream>>>((unsigned char*)Mb, src, off, b1, (unsigned*)Hb, N);
    stats_k<<<gStats, blk, 0, stream>>>(Hb, stats1, N);

    // ---- layer 2 ----
    mgemm_k<64, 2, false><<<gGemm, blk, 0, stream>>>(Hb, Wt2, Mb, stats1, g1, be1, invN,
                                                     X1, nullptr, N);
    agg64_k<<<gAgg, blk, 0, stream>>>((short*)Mb, src, off, b2, out, N);
}